// Round 11
// baseline (229.435 us; speedup 1.0000x reference)
//
#include <hip/hip_runtime.h>

// Problem constants (match reference setup_inputs()).
#define Bv 8
#define Nv 2048
#define Dv 8
#define Cv 128
#define Fv 256
#define Tv 4

// ---- walk config ----
#define CC    16               // c per walk block (4 float4 lanes)
#define TILE  64               // owned n per block
#define HALO  16               // 4 steps * max offset 4
#define LN    96               // loaded n
#define RS    128              // LDS row stride in floats (exact, no pad)
#define NT    32               // 2048/64 tiles, exact
// LDS = 96*128*4 = 49152 B = 48 KB EXACTLY -> 3 blocks/CU even with coarse
// LDS allocation granularity (r10 evidence: 50688 B behaved like a 2-block
// cap, occupancy 30%). Bank layout via XOR swizzle q ^= (row&7)<<4 instead
// of the +4 pad: publish quad = [ci4, (e^nl)&1], gather quad =
// [ci4, (sb^s1)&1] -> exactly 8 lanes/quad = b128 structural floor.
__global__ __launch_bounds__(LN * 4, 4)
void walk_kernel(const float* __restrict__ amps0,
                 const float* __restrict__ coins,
                 const int* __restrict__ swap_a,
                 const int* __restrict__ swap_b,
                 float* __restrict__ dsum)
{
    __shared__ float abuf[LN * RS];        // 48 KB

    const int bid  = blockIdx.x;
    const int b    = bid >> 8;             // 256 blocks per batch
    const int rem  = bid & 255;
    const int tile = rem >> 3;             // 0..31
    const int c0   = (rem & 7) * CC;       // 8 c-chunks of 16

    const int tid = threadIdx.x;
    const int ci4 = tid & 3;               // c = c0 + ci4*4 + 0..3
    const int nl  = tid >> 2;              // 0..95 local n slot

    const int n_load_start = tile * TILE - HALO;    // may be negative (mod N)
    const int ng = (n_load_start + nl) & (Nv - 1);  // global n of this slot

    float4 amp[Dv];     // per-thread amplitude state (8 d x 4 c)
    int    idx[Dv];     // LDS gather offsets (t-invariant, float index)

    // ---- load initial amplitudes (float4, coalesced 64B segments) ----
    {
        const float* srcf = amps0 + ((size_t)(b * Nv + ng) * Dv) * Cv + c0 + ci4 * 4;
        #pragma unroll
        for (int dd = 0; dd < Dv; ++dd)
            amp[dd] = *reinterpret_cast<const float4*>(srcf + (size_t)dd * Cv);
    }

    // ---- precompute gather offsets (t-invariant); LN=96 arithmetic wrap ----
    {
        const int* pa = swap_a + (size_t)(b * Nv + ng) * Dv;
        const int* pb = swap_b + (size_t)(b * Nv + ng) * Dv;
        #pragma unroll
        for (int dd = 0; dd < Dv; ++dd) {
            const int sa = pa[dd];
            const int sb = pb[dd];
            int s1 = sa - n_load_start;          // (-2032, 2064)
            if (s1 < 0)   s1 += Nv;              // [0, 2N)
            if (s1 >= Nv) s1 -= Nv;              // [0, N): mod-N offset in window
            if (s1 >= LN) s1 &= 63;              // halo-edge garbage -> any in-range
            // XOR-swizzled column (same function used on the publish side)
            idx[dd] = s1 * RS + ((sb * CC + ci4 * 4) ^ ((s1 & 7) << 4));
        }
    }

    // ---- coin coefficients: hoisted structure check (one-time) ----
    // Grover: cm = wd*I + wo*(J-I). Uniform addresses -> scalar loads.
    float wdv[Tv], wov[Tv];
    bool uni = true;
    #pragma unroll
    for (int tt = 0; tt < Tv; ++tt) {
        const float* cm = coins + tt * Dv * Dv;
        wdv[tt] = cm[0];
        wov[tt] = cm[1];
        #pragma unroll
        for (int i = 0; i < Dv; ++i)
            #pragma unroll
            for (int j = 0; j < Dv; ++j)
                uni = uni && (cm[i * Dv + j] == ((i == j) ? wdv[tt] : wov[tt]));
    }

    const int rowbase = nl * RS;
    const int swz     = (nl & 7) << 4;

    #pragma unroll
    for (int t = 0; t < Tv; ++t) {
        float4 a[Dv];
        if (uni) {
            // a[e] = fma(dw, amp[e], wo*s),  s = sum_d amp[d]
            const float wo = wov[t];
            const float dw = wdv[t] - wo;
            float4 s = amp[0];
            #pragma unroll
            for (int dd = 1; dd < Dv; ++dd) {
                s.x += amp[dd].x; s.y += amp[dd].y;
                s.z += amp[dd].z; s.w += amp[dd].w;
            }
            const float4 ws = {wo * s.x, wo * s.y, wo * s.z, wo * s.w};
            #pragma unroll
            for (int e = 0; e < Dv; ++e) {
                a[e].x = fmaf(dw, amp[e].x, ws.x);
                a[e].y = fmaf(dw, amp[e].y, ws.y);
                a[e].z = fmaf(dw, amp[e].z, ws.z);
                a[e].w = fmaf(dw, amp[e].w, ws.w);
            }
        } else {
            const float* cm = coins + t * Dv * Dv;
            #pragma unroll
            for (int e = 0; e < Dv; ++e) { a[e].x = a[e].y = a[e].z = a[e].w = 0.f; }
            #pragma unroll
            for (int dd = 0; dd < Dv; ++dd) {
                #pragma unroll
                for (int e = 0; e < Dv; ++e) {
                    const float w = cm[dd * Dv + e];
                    a[e].x += amp[dd].x * w;
                    a[e].y += amp[dd].y * w;
                    a[e].z += amp[dd].z * w;
                    a[e].w += amp[dd].w * w;
                }
            }
        }

        // publish: 8 x ds_write_b128, XOR-swizzled (structural-floor banking)
        #pragma unroll
        for (int e = 0; e < Dv; ++e)
            *reinterpret_cast<float4*>(abuf + rowbase + ((e * CC + ci4 * 4) ^ swz)) = a[e];
        __syncthreads();
        // gather: 8 x ds_read_b128
        #pragma unroll
        for (int dd = 0; dd < Dv; ++dd)
            amp[dd] = *reinterpret_cast<const float4*>(&abuf[idx[dd]]);
        __syncthreads();
    }

    // d[b,n,c] = sum_d amps^2, owned region only (float4 store)
    if (nl >= HALO && nl < HALO + TILE) {
        float4 s;
        s.x = s.y = s.z = s.w = 0.f;
        #pragma unroll
        for (int dd = 0; dd < Dv; ++dd) {
            s.x += amp[dd].x * amp[dd].x;
            s.y += amp[dd].y * amp[dd].y;
            s.z += amp[dd].z * amp[dd].z;
            s.w += amp[dd].w * amp[dd].w;
        }
        *reinterpret_cast<float4*>(dsum + (size_t)(b * Nv + ng) * Cv + c0 + ci4 * 4) = s;
    }
}

// ---- quant v3: zero workspace beyond dsum, zero atomics, single kernel ----
// out[b,c,f] = sum_n d[b,n,c] * neibs[b,n,f].
// Block = (b, c-pair): 512 blocks (2/CU), 256 threads = 4 waves.
// Wave w reduces n in [w*512, (w+1)*512); lane = f4 (64 lanes x float4 = 256 f).
// Per k: one float2 dsum load (wave-uniform addr -> broadcast) + one float4
// neibs load (1KB contiguous per wave) + 4 pk-fma. Cross-wave combine via
// 8 KB LDS, then direct coalesced float4 stores to out. No partials path
// needed for ANY ws_size (r5/r10 evidence: ws_size < 16 MiB forced the
// latency-bound 64-block fallback that cost ~80-100 us).
__global__ __launch_bounds__(256)
void quant_kernel(const float* __restrict__ dsum,
                  const float* __restrict__ neibs,
                  float* __restrict__ out)
{
    __shared__ float4 sbuf[4][2][64];      // 8 KB

    const int bid  = blockIdx.x;           // 0..511
    const int cp   = bid & 63;             // 64 c-pairs
    const int b    = bid >> 6;             // 8 batches
    const int tid  = threadIdx.x;
    const int lane = tid & 63;             // f4 index
    const int w    = tid >> 6;             // wave = n-chunk
    const int c0   = cp * 2;

    const float* dp = dsum  + ((size_t)(b * Nv + w * 512)) * Cv + c0;
    const float* np = neibs + ((size_t)(b * Nv + w * 512)) * Fv + lane * 4;

    float4 acc0 = {0.f, 0.f, 0.f, 0.f};
    float4 acc1 = {0.f, 0.f, 0.f, 0.f};

    #pragma unroll 4
    for (int k = 0; k < 512; ++k) {
        const float2 dv = *reinterpret_cast<const float2*>(dp + (size_t)k * Cv);
        const float4 nv = *reinterpret_cast<const float4*>(np + (size_t)k * Fv);
        acc0.x = fmaf(nv.x, dv.x, acc0.x);
        acc0.y = fmaf(nv.y, dv.x, acc0.y);
        acc0.z = fmaf(nv.z, dv.x, acc0.z);
        acc0.w = fmaf(nv.w, dv.x, acc0.w);
        acc1.x = fmaf(nv.x, dv.y, acc1.x);
        acc1.y = fmaf(nv.y, dv.y, acc1.y);
        acc1.z = fmaf(nv.z, dv.y, acc1.z);
        acc1.w = fmaf(nv.w, dv.y, acc1.w);
    }

    sbuf[w][0][lane] = acc0;
    sbuf[w][1][lane] = acc1;
    __syncthreads();

    if (tid < 128) {
        const int cc = tid >> 6;           // 0..1
        const int f4 = tid & 63;
        const float4 p0 = sbuf[0][cc][f4];
        const float4 p1 = sbuf[1][cc][f4];
        const float4 p2 = sbuf[2][cc][f4];
        const float4 p3 = sbuf[3][cc][f4];
        float4 s;
        s.x = (p0.x + p1.x) + (p2.x + p3.x);
        s.y = (p0.y + p1.y) + (p2.y + p3.y);
        s.z = (p0.z + p1.z) + (p2.z + p3.z);
        s.w = (p0.w + p1.w) + (p2.w + p3.w);
        *reinterpret_cast<float4*>(out + ((size_t)(b * Cv + c0 + cc)) * Fv + f4 * 4) = s;
    }
}

extern "C" void kernel_launch(void* const* d_in, const int* in_sizes, int n_in,
                              void* d_out, int out_size, void* d_ws, size_t ws_size,
                              hipStream_t stream)
{
    const float* amps   = (const float*)d_in[0];
    const float* neibs  = (const float*)d_in[1];
    const float* coins  = (const float*)d_in[2];
    const int*   swap_a = (const int*)d_in[3];
    const int*   swap_b = (const int*)d_in[4];
    float* out  = (float*)d_out;
    float* dsum = (float*)d_ws;        // 8 MiB, fits any ws_size >= 8 MiB

    walk_kernel<<<Bv * NT * (Cv / CC), LN * 4, 0, stream>>>(
        amps, coins, swap_a, swap_b, dsum);

    quant_kernel<<<Bv * 64, 256, 0, stream>>>(dsum, neibs, out);
}

// Round 12
// 199.059 us; speedup vs baseline: 1.1526x; 1.1526x over previous
//
#include <hip/hip_runtime.h>

// Problem constants (match reference setup_inputs()).
#define Bv 8
#define Nv 2048
#define Dv 8
#define Cv 128
#define Fv 256
#define Tv 4

// ---- walk config (UNCHANGED from r11 — quant was masking it; re-measure) ----
#define CC    16               // c per walk block (4 float4 lanes)
#define TILE  64               // owned n per block
#define HALO  16               // 4 steps * max offset 4
#define LN    96               // loaded n
#define RS    128              // LDS row stride in floats (exact, no pad)
#define NT    32               // 2048/64 tiles, exact
// LDS = 96*128*4 = 49152 B = 48 KB EXACTLY -> targets 3 blocks/CU under
// coarse LDS allocation granularity (r10: 50688 B behaved like a 2-block cap).
// Banking via XOR swizzle instead of pad: publish/gather both at the
// 8-lane/bank-quad b128 structural floor.
__global__ __launch_bounds__(LN * 4, 4)
void walk_kernel(const float* __restrict__ amps0,
                 const float* __restrict__ coins,
                 const int* __restrict__ swap_a,
                 const int* __restrict__ swap_b,
                 float* __restrict__ dsum)
{
    __shared__ float abuf[LN * RS];        // 48 KB

    const int bid  = blockIdx.x;
    const int b    = bid >> 8;             // 256 blocks per batch
    const int rem  = bid & 255;
    const int tile = rem >> 3;             // 0..31
    const int c0   = (rem & 7) * CC;       // 8 c-chunks of 16

    const int tid = threadIdx.x;
    const int ci4 = tid & 3;               // c = c0 + ci4*4 + 0..3
    const int nl  = tid >> 2;              // 0..95 local n slot

    const int n_load_start = tile * TILE - HALO;    // may be negative (mod N)
    const int ng = (n_load_start + nl) & (Nv - 1);  // global n of this slot

    float4 amp[Dv];     // per-thread amplitude state (8 d x 4 c)
    int    idx[Dv];     // LDS gather offsets (t-invariant, float index)

    // ---- load initial amplitudes (float4, coalesced 64B segments) ----
    {
        const float* srcf = amps0 + ((size_t)(b * Nv + ng) * Dv) * Cv + c0 + ci4 * 4;
        #pragma unroll
        for (int dd = 0; dd < Dv; ++dd)
            amp[dd] = *reinterpret_cast<const float4*>(srcf + (size_t)dd * Cv);
    }

    // ---- precompute gather offsets (t-invariant); LN=96 arithmetic wrap ----
    {
        const int* pa = swap_a + (size_t)(b * Nv + ng) * Dv;
        const int* pb = swap_b + (size_t)(b * Nv + ng) * Dv;
        #pragma unroll
        for (int dd = 0; dd < Dv; ++dd) {
            const int sa = pa[dd];
            const int sb = pb[dd];
            int s1 = sa - n_load_start;          // (-2032, 2064)
            if (s1 < 0)   s1 += Nv;              // [0, 2N)
            if (s1 >= Nv) s1 -= Nv;              // [0, N): mod-N offset in window
            if (s1 >= LN) s1 &= 63;              // halo-edge garbage -> any in-range
            // XOR-swizzled column (same function used on the publish side)
            idx[dd] = s1 * RS + ((sb * CC + ci4 * 4) ^ ((s1 & 7) << 4));
        }
    }

    // ---- coin coefficients: hoisted structure check (one-time) ----
    float wdv[Tv], wov[Tv];
    bool uni = true;
    #pragma unroll
    for (int tt = 0; tt < Tv; ++tt) {
        const float* cm = coins + tt * Dv * Dv;
        wdv[tt] = cm[0];
        wov[tt] = cm[1];
        #pragma unroll
        for (int i = 0; i < Dv; ++i)
            #pragma unroll
            for (int j = 0; j < Dv; ++j)
                uni = uni && (cm[i * Dv + j] == ((i == j) ? wdv[tt] : wov[tt]));
    }

    const int rowbase = nl * RS;
    const int swz     = (nl & 7) << 4;

    #pragma unroll
    for (int t = 0; t < Tv; ++t) {
        float4 a[Dv];
        if (uni) {
            const float wo = wov[t];
            const float dw = wdv[t] - wo;
            float4 s = amp[0];
            #pragma unroll
            for (int dd = 1; dd < Dv; ++dd) {
                s.x += amp[dd].x; s.y += amp[dd].y;
                s.z += amp[dd].z; s.w += amp[dd].w;
            }
            const float4 ws = {wo * s.x, wo * s.y, wo * s.z, wo * s.w};
            #pragma unroll
            for (int e = 0; e < Dv; ++e) {
                a[e].x = fmaf(dw, amp[e].x, ws.x);
                a[e].y = fmaf(dw, amp[e].y, ws.y);
                a[e].z = fmaf(dw, amp[e].z, ws.z);
                a[e].w = fmaf(dw, amp[e].w, ws.w);
            }
        } else {
            const float* cm = coins + t * Dv * Dv;
            #pragma unroll
            for (int e = 0; e < Dv; ++e) { a[e].x = a[e].y = a[e].z = a[e].w = 0.f; }
            #pragma unroll
            for (int dd = 0; dd < Dv; ++dd) {
                #pragma unroll
                for (int e = 0; e < Dv; ++e) {
                    const float w = cm[dd * Dv + e];
                    a[e].x += amp[dd].x * w;
                    a[e].y += amp[dd].y * w;
                    a[e].z += amp[dd].z * w;
                    a[e].w += amp[dd].w * w;
                }
            }
        }

        // publish: 8 x ds_write_b128, XOR-swizzled (structural-floor banking)
        #pragma unroll
        for (int e = 0; e < Dv; ++e)
            *reinterpret_cast<float4*>(abuf + rowbase + ((e * CC + ci4 * 4) ^ swz)) = a[e];
        __syncthreads();
        // gather: 8 x ds_read_b128
        #pragma unroll
        for (int dd = 0; dd < Dv; ++dd)
            amp[dd] = *reinterpret_cast<const float4*>(&abuf[idx[dd]]);
        __syncthreads();
    }

    // d[b,n,c] = sum_d amps^2, owned region only (float4 store)
    if (nl >= HALO && nl < HALO + TILE) {
        float4 s;
        s.x = s.y = s.z = s.w = 0.f;
        #pragma unroll
        for (int dd = 0; dd < Dv; ++dd) {
            s.x += amp[dd].x * amp[dd].x;
            s.y += amp[dd].y * amp[dd].y;
            s.z += amp[dd].z * amp[dd].z;
            s.w += amp[dd].w * amp[dd].w;
        }
        *reinterpret_cast<float4*>(dsum + (size_t)(b * Nv + ng) * Cv + c0 + ci4 * 4) = s;
    }
}

// ---- quant v4: c-oct x f-half blocking + XCD-pinned batches ----
// out[b,c,f] = sum_n d[b,n,c] * neibs[b,n,f].
// Block = (b, c-oct of 8, f-half of 128): grid 256 x 1024 thr (16 waves).
// b = bid & 7 -> (round-robin dispatch) all blocks of batch b land on XCD b;
// working set neibs[b] (2 MB) + dsum[b] (1 MB) fits the 4 MB XCD L2 ->
// r11's 98 MB FETCH (64-block neibs re-stream thrash) drops to ~25 MB.
// Wave w = n-chunk of 128. Lane: ch = lane>>5 (c-quad), f4 = lane&31.
// Per k: one float4 d-load (uniform per half-wave) + one float4 neibs load
// (512B/wave, halves merge) + 16 fma. Cross-wave combine via 64 KB LDS
// [w][slot] (both sides at the 8-lane/quad b128 floor), coalesced out store.
// Zero workspace beyond dsum, zero atomics, any ws_size.
__global__ __launch_bounds__(1024, 4)
void quant_kernel(const float* __restrict__ dsum,
                  const float* __restrict__ neibs,
                  float* __restrict__ out)
{
    __shared__ float4 sbuf[16][256];       // 64 KB: [wave][slot]

    const int bid = blockIdx.x;
    const int b   = bid & 7;               // XCD pin
    const int r   = bid >> 3;
    const int co  = r & 15;                // 16 c-octs
    const int fh  = r >> 4;                // 2 f-halves
    const int c0  = co * 8;
    const int f0  = fh * 128;

    const int tid  = threadIdx.x;
    const int w    = tid >> 6;             // 16 waves = n-chunks of 128
    const int lane = tid & 63;
    const int ch   = lane >> 5;            // c-quad: c0 + ch*4 + 0..3
    const int f4   = lane & 31;            // f = f0 + f4*4 + 0..3

    const float* dp = dsum  + ((size_t)(b * Nv + w * 128)) * Cv + c0 + ch * 4;
    const float* np = neibs + ((size_t)(b * Nv + w * 128)) * Fv + f0 + f4 * 4;

    float4 acc[4];
    #pragma unroll
    for (int j = 0; j < 4; ++j) acc[j] = (float4){0.f, 0.f, 0.f, 0.f};

    #pragma unroll 4
    for (int k = 0; k < 128; ++k) {
        const float4 dv = *reinterpret_cast<const float4*>(dp + (size_t)k * Cv);
        const float4 nv = *reinterpret_cast<const float4*>(np + (size_t)k * Fv);
        acc[0].x = fmaf(nv.x, dv.x, acc[0].x);
        acc[0].y = fmaf(nv.y, dv.x, acc[0].y);
        acc[0].z = fmaf(nv.z, dv.x, acc[0].z);
        acc[0].w = fmaf(nv.w, dv.x, acc[0].w);
        acc[1].x = fmaf(nv.x, dv.y, acc[1].x);
        acc[1].y = fmaf(nv.y, dv.y, acc[1].y);
        acc[1].z = fmaf(nv.z, dv.y, acc[1].z);
        acc[1].w = fmaf(nv.w, dv.y, acc[1].w);
        acc[2].x = fmaf(nv.x, dv.z, acc[2].x);
        acc[2].y = fmaf(nv.y, dv.z, acc[2].y);
        acc[2].z = fmaf(nv.z, dv.z, acc[2].z);
        acc[2].w = fmaf(nv.w, dv.z, acc[2].w);
        acc[3].x = fmaf(nv.x, dv.w, acc[3].x);
        acc[3].y = fmaf(nv.y, dv.w, acc[3].y);
        acc[3].z = fmaf(nv.z, dv.w, acc[3].z);
        acc[3].w = fmaf(nv.w, dv.w, acc[3].w);
    }

    // partials: slot = c_local*32 + f4, c_local = ch*4 + cj
    #pragma unroll
    for (int cj = 0; cj < 4; ++cj)
        sbuf[w][(ch * 4 + cj) * 32 + f4] = acc[cj];
    __syncthreads();

    // fold 16 waves; 256 reader threads, coalesced float4 out stores
    if (tid < 256) {
        const int s       = tid;
        const int c_local = s >> 5;
        const int f4r     = s & 31;
        float4 t = sbuf[0][s];
        #pragma unroll
        for (int ww = 1; ww < 16; ++ww) {
            const float4 p = sbuf[ww][s];
            t.x += p.x; t.y += p.y; t.z += p.z; t.w += p.w;
        }
        *reinterpret_cast<float4*>(
            out + ((size_t)(b * Cv + c0 + c_local)) * Fv + f0 + f4r * 4) = t;
    }
}

extern "C" void kernel_launch(void* const* d_in, const int* in_sizes, int n_in,
                              void* d_out, int out_size, void* d_ws, size_t ws_size,
                              hipStream_t stream)
{
    const float* amps   = (const float*)d_in[0];
    const float* neibs  = (const float*)d_in[1];
    const float* coins  = (const float*)d_in[2];
    const int*   swap_a = (const int*)d_in[3];
    const int*   swap_b = (const int*)d_in[4];
    float* out  = (float*)d_out;
    float* dsum = (float*)d_ws;        // 8 MiB, fits any ws_size >= 8 MiB

    walk_kernel<<<Bv * NT * (Cv / CC), LN * 4, 0, stream>>>(
        amps, coins, swap_a, swap_b, dsum);

    quant_kernel<<<Bv * 16 * 2, 1024, 0, stream>>>(dsum, neibs, out);
}